// Round 6
// baseline (183.835 us; speedup 1.0000x reference)
//
#include <hip/hip_runtime.h>
#include <hip/hip_bf16.h>
#include <cmath>

typedef float f32x4 __attribute__((ext_vector_type(4)));
typedef float f32x16 __attribute__((ext_vector_type(16)));
typedef __bf16 bf16x2 __attribute__((ext_vector_type(2)));
typedef __bf16 bf16x4 __attribute__((ext_vector_type(4)));
typedef __bf16 bf16x8 __attribute__((ext_vector_type(8)));

#define C_IN 384
#define C_OUT 384
#define SPB 4096      // spatial per batch image (64*64)
#define NPIX 131072   // 32 * 4096 total pixels
#define BP 64         // pixels per GEMM block
#define LDK 392       // padded Xs row (bf16): 784 B, 16B-aligned

// ---------------------------------------------------------------------------
// prep: Wp[o][c] = bf16(W[o][c]*gamma[c]); t1[o] = sum_c float(Wp[o][c]);
//       t2[o] = sum_c beta[c]*W[o][c] + b[o]
// ---------------------------------------------------------------------------
__global__ __launch_bounds__(128) void ppl_prep_kernel(const float* __restrict__ W,
                                                       const float* __restrict__ gamma,
                                                       const float* __restrict__ beta,
                                                       const float* __restrict__ bias,
                                                       __bf16* __restrict__ Wp,
                                                       float* __restrict__ t1,
                                                       float* __restrict__ t2) {
  const int o = blockIdx.x;
  const int t = threadIdx.x;
  const float* row = W + o * C_IN;
  float s1 = 0.f, s2 = 0.f;
  for (int c = t; c < C_IN; c += 128) {
    const float w = row[c];
    const __bf16 wq = (__bf16)(w * gamma[c]);
    Wp[o * C_IN + c] = wq;
    s1 += (float)wq;
    s2 += beta[c] * w;
  }
#pragma unroll
  for (int off = 32; off > 0; off >>= 1) {
    s1 += __shfl_down(s1, off);
    s2 += __shfl_down(s2, off);
  }
  __shared__ float red[2][2];
  if ((t & 63) == 0) { red[t >> 6][0] = s1; red[t >> 6][1] = s2; }
  __syncthreads();
  if (t == 0) {
    t1[o] = red[0][0] + red[1][0];
    t2[o] = red[0][1] + red[1][1] + bias[o];
  }
}

// fast GELU: tanh-form via sigmoid; validated R2-R4 (absmax unchanged at 0.0156)
__device__ __forceinline__ float gelu_fast(float v) {
  const float u = 0.7978845608028654f * v * __builtin_fmaf(0.044715f * v, v, 1.0f);
  const float e = __expf(-2.0f * u);
  return v * __builtin_amdgcn_rcpf(1.0f + e);
}

// ---------------------------------------------------------------------------
// Pass 1: LN stats + bf16 cast, pure streaming.
//   Block = 512 threads (8 waves) x 256 pixels; wave w owns channels
//   [48w, 48w+48).  Thread = 4 consecutive pixels (float4 loads, bf16x4
//   stores, both fully coalesced).  fp32 sum/sumsq -> LDS reduce -> mu/rs.
// ---------------------------------------------------------------------------
__global__ __launch_bounds__(512) void ppl_stats_cast_kernel(const float* __restrict__ x,
                                                             __bf16* __restrict__ xb,
                                                             float* __restrict__ mu,
                                                             float* __restrict__ rs) {
  __shared__ float sS[8][256];
  __shared__ float sQ[8][256];
  const int tid = threadIdx.x;
  const int w = tid >> 6;
  const int lane = tid & 63;
  const int p0 = blockIdx.x * 256;
  const int b = p0 >> 12;
  const int s0 = p0 & 4095;
  const int c0 = w * 48;
  const float* xp = x + (((size_t)(b * C_IN + c0)) << 12) + s0 + 4 * lane;
  __bf16* xbp = xb + (((size_t)(b * C_IN + c0)) << 12) + s0 + 4 * lane;

  f32x4 ssv = {0.f, 0.f, 0.f, 0.f};
  f32x4 qqv = {0.f, 0.f, 0.f, 0.f};
#pragma unroll
  for (int i = 0; i < 48; i += 12) {
    f32x4 L[12];
#pragma unroll
    for (int j = 0; j < 12; ++j)
      L[j] = *reinterpret_cast<const f32x4*>(xp + ((size_t)(i + j) << 12));
#pragma unroll
    for (int j = 0; j < 12; ++j) {
      const f32x4 v = L[j];
      ssv += v;
      qqv += v * v;
      bf16x4 pk;
      pk[0] = (__bf16)v[0];
      pk[1] = (__bf16)v[1];
      pk[2] = (__bf16)v[2];
      pk[3] = (__bf16)v[3];
      *reinterpret_cast<bf16x4*>(xbp + ((size_t)(i + j) << 12)) = pk;
    }
  }
  *reinterpret_cast<f32x4*>(&sS[w][4 * lane]) = ssv;
  *reinterpret_cast<f32x4*>(&sQ[w][4 * lane]) = qqv;
  __syncthreads();
  if (tid < 256) {
    float st = 0.f, qt = 0.f;
#pragma unroll
    for (int r = 0; r < 8; ++r) {
      st += sS[r][tid];
      qt += sQ[r][tid];
    }
    const float m = st * (1.0f / C_IN);
    mu[p0 + tid] = m;
    rs[p0 + tid] = rsqrtf(qt * (1.0f / C_IN) - m * m + 1e-5f);
  }
}

// ---------------------------------------------------------------------------
// Pass 2: GEMM + LN epilogue + GELU.  Input xb is bf16 [c][s] (L3-resident).
//   Block = 64 px x all 384 outs.  Staging: [c][s]->[px][c] LDS transpose
//   (bf16x8 coalesced reads, b32 LDS writes).  k-loop: barrier-free
//   32x32x16 MFMA, W' ping-pong from L2 (R4's proven loop).  Epilogue:
//   y = rs*(acc - mu*t1[o]) + t2[o], gelu_fast, f32x4 NCHW stores.
// ---------------------------------------------------------------------------
__global__ __launch_bounds__(256, 3) void ppl_gemm2_kernel(const __bf16* __restrict__ xb,
                                                           const __bf16* __restrict__ Wp,
                                                           const float* __restrict__ mug,
                                                           const float* __restrict__ rsg,
                                                           const float* __restrict__ t1g,
                                                           const float* __restrict__ t2g,
                                                           float* __restrict__ out) {
  __shared__ __bf16 Xs[BP][LDK];
  __shared__ float mu_s[BP];
  __shared__ float rs_s[BP];

  const int tid = threadIdx.x;
  const int w = tid >> 6;
  const int lane = tid & 63;
  const int col = lane & 31;
  const int hi = lane >> 5;
  const int p0 = blockIdx.x * BP;
  const int b = p0 >> 12;
  const int s0 = p0 & 4095;
  const int ob = w * 96;

  if (tid < BP) {
    mu_s[tid] = mug[p0 + tid];
    rs_s[tid] = rsg[p0 + tid];
  }

  // ---- staging with transpose ----
  const int chg = tid >> 3;        // 0..31
  const int px8 = (tid & 7) * 8;   // pixel group base
  const __bf16* xsrc = xb + (((size_t)(b * C_IN)) << 12) + s0 + px8;
#pragma unroll
  for (int i = 0; i < 6; ++i) {
    const int c = 2 * chg + 64 * i;
    const bf16x8 v0 = *reinterpret_cast<const bf16x8*>(xsrc + ((size_t)c << 12));
    const bf16x8 v1 = *reinterpret_cast<const bf16x8*>(xsrc + ((size_t)(c + 1) << 12));
#pragma unroll
    for (int r = 0; r < 8; ++r) {
      bf16x2 pr;
      pr[0] = v0[r];
      pr[1] = v1[r];
      *reinterpret_cast<bf16x2*>(&Xs[px8 + r][c]) = pr;
    }
  }
  __syncthreads();

  // ---- barrier-free k-loop, 32x32x16 MFMA, W ping-pong prefetch ----
  const __bf16* wp0 = Wp + (size_t)(ob + col) * C_IN + hi * 8;
  const __bf16* wp1 = wp0 + 32 * C_IN;
  const __bf16* wp2 = wp0 + 64 * C_IN;
  const __bf16* xs0 = &Xs[col][hi * 8];
  const __bf16* xs1 = &Xs[32 + col][hi * 8];

  f32x16 acc[2][3];
#pragma unroll
  for (int m = 0; m < 2; ++m)
#pragma unroll
    for (int n = 0; n < 3; ++n)
#pragma unroll
      for (int r = 0; r < 16; ++r) acc[m][n][r] = 0.f;

#define LOADB(dst, kk)                                     \
  {                                                        \
    dst[0] = *reinterpret_cast<const bf16x8*>(wp0 + (kk)); \
    dst[1] = *reinterpret_cast<const bf16x8*>(wp1 + (kk)); \
    dst[2] = *reinterpret_cast<const bf16x8*>(wp2 + (kk)); \
  }
#define STEP(bb, kk)                                                                    \
  {                                                                                     \
    const bf16x8 a0 = *reinterpret_cast<const bf16x8*>(xs0 + (kk));                     \
    const bf16x8 a1 = *reinterpret_cast<const bf16x8*>(xs1 + (kk));                     \
    acc[0][0] = __builtin_amdgcn_mfma_f32_32x32x16_bf16(a0, bb[0], acc[0][0], 0, 0, 0); \
    acc[0][1] = __builtin_amdgcn_mfma_f32_32x32x16_bf16(a0, bb[1], acc[0][1], 0, 0, 0); \
    acc[0][2] = __builtin_amdgcn_mfma_f32_32x32x16_bf16(a0, bb[2], acc[0][2], 0, 0, 0); \
    acc[1][0] = __builtin_amdgcn_mfma_f32_32x32x16_bf16(a1, bb[0], acc[1][0], 0, 0, 0); \
    acc[1][1] = __builtin_amdgcn_mfma_f32_32x32x16_bf16(a1, bb[1], acc[1][1], 0, 0, 0); \
    acc[1][2] = __builtin_amdgcn_mfma_f32_32x32x16_bf16(a1, bb[2], acc[1][2], 0, 0, 0); \
  }

  {
    bf16x8 bA[3], bB[3];
    LOADB(bA, 0);
#pragma unroll
    for (int it = 0; it < 12; ++it) {
      const int k = it * 32;
      LOADB(bB, k + 16);
      STEP(bA, k);
      if (it < 11) LOADB(bA, k + 32);
      STEP(bB, k + 16);
    }
  }
#undef LOADB
#undef STEP

  // ---- epilogue ----
  const float t1v[3] = {t1g[ob + col], t1g[ob + 32 + col], t1g[ob + 64 + col]};
  const float t2v[3] = {t2g[ob + col], t2g[ob + 32 + col], t2g[ob + 64 + col]};
  float* outp = out + (((size_t)(b * C_OUT + ob + col)) << 12) + s0;

#pragma unroll
  for (int nf = 0; nf < 3; ++nf) {
    float* op = outp + ((size_t)nf << 17);  // += 32 out-channels
#pragma unroll
    for (int m = 0; m < 2; ++m) {
#pragma unroll
      for (int qd = 0; qd < 4; ++qd) {
        const int pr = m * 32 + qd * 8 + hi * 4;
        const f32x4 mu4 = *reinterpret_cast<const f32x4*>(&mu_s[pr]);
        const f32x4 rs4 = *reinterpret_cast<const f32x4*>(&rs_s[pr]);
        f32x4 y;
#pragma unroll
        for (int r = 0; r < 4; ++r) {
          const float val = rs4[r] * (acc[m][nf][qd * 4 + r] - mu4[r] * t1v[nf]) + t2v[nf];
          y[r] = gelu_fast(val);
        }
        *reinterpret_cast<f32x4*>(op + pr) = y;
      }
    }
  }
}

// ---------------------------------------------------------------------------
// Fallback (R4): fully fused single-pass kernel, used only if ws_size is too
// small for the bf16 x copy.  Measured 193 us.
// ---------------------------------------------------------------------------
__global__ __launch_bounds__(256, 3) void ppl_fused_kernel(const float* __restrict__ x,
                                                           const __bf16* __restrict__ Wp,
                                                           const float* __restrict__ t1g,
                                                           const float* __restrict__ t2g,
                                                           float* __restrict__ out) {
  __shared__ __bf16 Xs[BP][LDK];
  __shared__ float sS[4][BP];
  __shared__ float sQ[4][BP];
  __shared__ float mu_s[BP];
  __shared__ float rs_s[BP];

  const int tid = threadIdx.x;
  const int w = tid >> 6;
  const int lane = tid & 63;
  const int q = tid & 15;
  const int j = tid >> 4;
  const int col = lane & 31;
  const int hi = lane >> 5;
  const int p0 = blockIdx.x * BP;
  const int b = p0 >> 12;
  const int s0 = p0 & 4095;
  const int ob = w * 96;

  const float* xq = x + (size_t)b * (C_IN * SPB) + s0 + 4 * q;

  f32x4 LA[12], LB[12];
#pragma unroll
  for (int i = 0; i < 3; ++i)
#pragma unroll
    for (int m = 0; m < 4; ++m)
      LA[i * 4 + m] = *reinterpret_cast<const f32x4*>(xq + (size_t)(64 * i + 4 * j + m) * SPB);
#pragma unroll
  for (int i = 0; i < 3; ++i)
#pragma unroll
    for (int m = 0; m < 4; ++m)
      LB[i * 4 + m] = *reinterpret_cast<const f32x4*>(xq + (size_t)(64 * (i + 3) + 4 * j + m) * SPB);

  float ss[4] = {0.f, 0.f, 0.f, 0.f};
  float qq[4] = {0.f, 0.f, 0.f, 0.f};

#define PROCESS(L, ibase)                                                   \
  {                                                                         \
    _Pragma("unroll") for (int i = 0; i < 3; ++i) {                         \
      _Pragma("unroll") for (int r = 0; r < 4; ++r) {                       \
        const float f0 = L[i * 4 + 0][r];                                   \
        const float f1 = L[i * 4 + 1][r];                                   \
        const float f2 = L[i * 4 + 2][r];                                   \
        const float f3 = L[i * 4 + 3][r];                                   \
        ss[r] += (f0 + f1) + (f2 + f3);                                     \
        qq[r] += (f0 * f0 + f1 * f1) + (f2 * f2 + f3 * f3);                 \
        bf16x4 pk;                                                          \
        pk[0] = (__bf16)f0; pk[1] = (__bf16)f1;                             \
        pk[2] = (__bf16)f2; pk[3] = (__bf16)f3;                             \
        *reinterpret_cast<bf16x4*>(&Xs[4 * q + r][64 * ((ibase) + i) + 4 * j]) = pk; \
      }                                                                     \
    }                                                                       \
  }
  PROCESS(LA, 0)
  PROCESS(LB, 3)
#undef PROCESS

#pragma unroll
  for (int r = 0; r < 4; ++r) {
    ss[r] += __shfl_xor(ss[r], 16);
    ss[r] += __shfl_xor(ss[r], 32);
    qq[r] += __shfl_xor(qq[r], 16);
    qq[r] += __shfl_xor(qq[r], 32);
  }
  if (lane < 16) {
#pragma unroll
    for (int r = 0; r < 4; ++r) {
      sS[w][4 * lane + r] = ss[r];
      sQ[w][4 * lane + r] = qq[r];
    }
  }
  __syncthreads();
  if (tid < BP) {
    const float st = sS[0][tid] + sS[1][tid] + sS[2][tid] + sS[3][tid];
    const float qt = sQ[0][tid] + sQ[1][tid] + sQ[2][tid] + sQ[3][tid];
    const float m = st * (1.0f / C_IN);
    mu_s[tid] = m;
    rs_s[tid] = rsqrtf(qt * (1.0f / C_IN) - m * m + 1e-5f);
  }
  __syncthreads();

  const __bf16* wp0 = Wp + (size_t)(ob + col) * C_IN + hi * 8;
  const __bf16* wp1 = wp0 + 32 * C_IN;
  const __bf16* wp2 = wp0 + 64 * C_IN;
  const __bf16* xs0 = &Xs[col][hi * 8];
  const __bf16* xs1 = &Xs[32 + col][hi * 8];

  f32x16 acc[2][3];
#pragma unroll
  for (int m = 0; m < 2; ++m)
#pragma unroll
    for (int n = 0; n < 3; ++n)
#pragma unroll
      for (int r = 0; r < 16; ++r) acc[m][n][r] = 0.f;

#define LOADB(dst, kk)                                     \
  {                                                        \
    dst[0] = *reinterpret_cast<const bf16x8*>(wp0 + (kk)); \
    dst[1] = *reinterpret_cast<const bf16x8*>(wp1 + (kk)); \
    dst[2] = *reinterpret_cast<const bf16x8*>(wp2 + (kk)); \
  }
#define STEP(bb, kk)                                                                    \
  {                                                                                     \
    const bf16x8 a0 = *reinterpret_cast<const bf16x8*>(xs0 + (kk));                     \
    const bf16x8 a1 = *reinterpret_cast<const bf16x8*>(xs1 + (kk));                     \
    acc[0][0] = __builtin_amdgcn_mfma_f32_32x32x16_bf16(a0, bb[0], acc[0][0], 0, 0, 0); \
    acc[0][1] = __builtin_amdgcn_mfma_f32_32x32x16_bf16(a0, bb[1], acc[0][1], 0, 0, 0); \
    acc[0][2] = __builtin_amdgcn_mfma_f32_32x32x16_bf16(a0, bb[2], acc[0][2], 0, 0, 0); \
    acc[1][0] = __builtin_amdgcn_mfma_f32_32x32x16_bf16(a1, bb[0], acc[1][0], 0, 0, 0); \
    acc[1][1] = __builtin_amdgcn_mfma_f32_32x32x16_bf16(a1, bb[1], acc[1][1], 0, 0, 0); \
    acc[1][2] = __builtin_amdgcn_mfma_f32_32x32x16_bf16(a1, bb[2], acc[1][2], 0, 0, 0); \
  }
  {
    bf16x8 bA[3], bB[3];
    LOADB(bA, 0);
#pragma unroll
    for (int it = 0; it < 12; ++it) {
      const int k = it * 32;
      LOADB(bB, k + 16);
      STEP(bA, k);
      if (it < 11) LOADB(bA, k + 32);
      STEP(bB, k + 16);
    }
  }
#undef LOADB
#undef STEP

  const float t1v[3] = {t1g[ob + col], t1g[ob + 32 + col], t1g[ob + 64 + col]};
  const float t2v[3] = {t2g[ob + col], t2g[ob + 32 + col], t2g[ob + 64 + col]};
  float* outp = out + (((size_t)(b * C_OUT + ob + col)) << 12) + s0;
#pragma unroll
  for (int nf = 0; nf < 3; ++nf) {
    float* op = outp + ((size_t)nf << 17);
#pragma unroll
    for (int m = 0; m < 2; ++m) {
#pragma unroll
      for (int qd = 0; qd < 4; ++qd) {
        const int pr = m * 32 + qd * 8 + hi * 4;
        const f32x4 mu4 = *reinterpret_cast<const f32x4*>(&mu_s[pr]);
        const f32x4 rs4 = *reinterpret_cast<const f32x4*>(&rs_s[pr]);
        f32x4 y;
#pragma unroll
        for (int r = 0; r < 4; ++r) {
          const float val = rs4[r] * (acc[m][nf][qd * 4 + r] - mu4[r] * t1v[nf]) + t2v[nf];
          y[r] = gelu_fast(val);
        }
        *reinterpret_cast<f32x4*>(op + pr) = y;
      }
    }
  }
}

// ---------------------------------------------------------------------------
extern "C" void kernel_launch(void* const* d_in, const int* in_sizes, int n_in,
                              void* d_out, int out_size, void* d_ws, size_t ws_size,
                              hipStream_t stream) {
  const float* x = (const float*)d_in[0];
  const float* gamma = (const float*)d_in[1];
  const float* beta = (const float*)d_in[2];
  const float* W = (const float*)d_in[3];
  const float* bias = (const float*)d_in[4];
  float* out = (float*)d_out;

  // workspace layout
  __bf16* Wp = (__bf16*)d_ws;                   // 294912 B
  float* t1 = (float*)(Wp + C_OUT * C_IN);      // 1536 B
  float* t2 = t1 + C_OUT;                       // 1536 B
  float* mu = t2 + C_OUT;                       // NPIX floats
  float* rs = mu + NPIX;                        // NPIX floats
  __bf16* xb = (__bf16*)(rs + NPIX);            // NPIX * C_IN bf16 = 100.7 MB

  const size_t need = (size_t)C_OUT * C_IN * 2 + 2 * C_OUT * 4 +
                      2 * (size_t)NPIX * 4 + (size_t)NPIX * C_IN * 2;

  ppl_prep_kernel<<<C_OUT, 128, 0, stream>>>(W, gamma, beta, bias, Wp, t1, t2);

  if (ws_size >= need) {
    ppl_stats_cast_kernel<<<NPIX / 256, 512, 0, stream>>>(x, xb, mu, rs);
    ppl_gemm2_kernel<<<NPIX / BP, 256, 0, stream>>>(xb, Wp, mu, rs, t1, t2, out);
  } else {
    ppl_fused_kernel<<<NPIX / BP, 256, 0, stream>>>(x, Wp, t1, t2, out);
  }
}

// Round 7
// 175.773 us; speedup vs baseline: 1.0459x; 1.0459x over previous
//
#include <hip/hip_runtime.h>
#include <hip/hip_bf16.h>
#include <cmath>

typedef float f32x4 __attribute__((ext_vector_type(4)));
typedef float f32x16 __attribute__((ext_vector_type(16)));
typedef __bf16 bf16x2 __attribute__((ext_vector_type(2)));
typedef __bf16 bf16x4 __attribute__((ext_vector_type(4)));
typedef __bf16 bf16x8 __attribute__((ext_vector_type(8)));

#define C_IN 384
#define C_OUT 384
#define SPB 4096      // spatial per batch image (64*64)
#define NPIX 131072   // 32 * 4096 total pixels
#define BP 64         // pixels per GEMM block
#define LDK 392       // fallback kernel's padded Xs row
#define ROW2 34       // gemm3 LDS row stride in bf16 (17 words: bijective banks)

// ---------------------------------------------------------------------------
// prep: Wp[o][c] = bf16(W[o][c]*gamma[c])  (row-major, for fallback)
//       Wt tiled: Wt[((o>>5)*48 + (c>>3))*256 + (o&31)*8 + (c&7)]  (for gemm3)
//       t1[o] = sum_c float(Wp[o][c]);  t2[o] = sum_c beta[c]*W[o][c] + b[o]
// ---------------------------------------------------------------------------
__global__ __launch_bounds__(128) void ppl_prep_kernel(const float* __restrict__ W,
                                                       const float* __restrict__ gamma,
                                                       const float* __restrict__ beta,
                                                       const float* __restrict__ bias,
                                                       __bf16* __restrict__ Wp,
                                                       __bf16* __restrict__ Wt,
                                                       float* __restrict__ t1,
                                                       float* __restrict__ t2) {
  const int o = blockIdx.x;
  const int t = threadIdx.x;
  const float* row = W + o * C_IN;
  float s1 = 0.f, s2 = 0.f;
  for (int c = t; c < C_IN; c += 128) {
    const float w = row[c];
    const __bf16 wq = (__bf16)(w * gamma[c]);
    Wp[o * C_IN + c] = wq;
    Wt[(((size_t)(o >> 5) * 48 + (c >> 3)) << 8) + ((o & 31) << 3) + (c & 7)] = wq;
    s1 += (float)wq;
    s2 += beta[c] * w;
  }
#pragma unroll
  for (int off = 32; off > 0; off >>= 1) {
    s1 += __shfl_down(s1, off);
    s2 += __shfl_down(s2, off);
  }
  __shared__ float red[2][2];
  if ((t & 63) == 0) { red[t >> 6][0] = s1; red[t >> 6][1] = s2; }
  __syncthreads();
  if (t == 0) {
    t1[o] = red[0][0] + red[1][0];
    t2[o] = red[0][1] + red[1][1] + bias[o];
  }
}

// fast GELU: tanh-form via sigmoid; validated R2-R5 (absmax unchanged at 0.0156)
__device__ __forceinline__ float gelu_fast(float v) {
  const float u = 0.7978845608028654f * v * __builtin_fmaf(0.044715f * v, v, 1.0f);
  const float e = __expf(-2.0f * u);
  return v * __builtin_amdgcn_rcpf(1.0f + e);
}

// ---------------------------------------------------------------------------
// Pass 1 (unchanged from R5, measured ~36 us): LN stats + bf16 cast, streaming.
// ---------------------------------------------------------------------------
__global__ __launch_bounds__(512) void ppl_stats_cast_kernel(const float* __restrict__ x,
                                                             __bf16* __restrict__ xb,
                                                             float* __restrict__ mu,
                                                             float* __restrict__ rs) {
  __shared__ float sS[8][256];
  __shared__ float sQ[8][256];
  const int tid = threadIdx.x;
  const int w = tid >> 6;
  const int lane = tid & 63;
  const int p0 = blockIdx.x * 256;
  const int b = p0 >> 12;
  const int s0 = p0 & 4095;
  const int c0 = w * 48;
  const float* xp = x + (((size_t)(b * C_IN + c0)) << 12) + s0 + 4 * lane;
  __bf16* xbp = xb + (((size_t)(b * C_IN + c0)) << 12) + s0 + 4 * lane;

  f32x4 ssv = {0.f, 0.f, 0.f, 0.f};
  f32x4 qqv = {0.f, 0.f, 0.f, 0.f};
#pragma unroll
  for (int i = 0; i < 48; i += 12) {
    f32x4 L[12];
#pragma unroll
    for (int j = 0; j < 12; ++j)
      L[j] = *reinterpret_cast<const f32x4*>(xp + ((size_t)(i + j) << 12));
#pragma unroll
    for (int j = 0; j < 12; ++j) {
      const f32x4 v = L[j];
      ssv += v;
      qqv += v * v;
      bf16x4 pk;
      pk[0] = (__bf16)v[0];
      pk[1] = (__bf16)v[1];
      pk[2] = (__bf16)v[2];
      pk[3] = (__bf16)v[3];
      *reinterpret_cast<bf16x4*>(xbp + ((size_t)(i + j) << 12)) = pk;
    }
  }
  *reinterpret_cast<f32x4*>(&sS[w][4 * lane]) = ssv;
  *reinterpret_cast<f32x4*>(&sQ[w][4 * lane]) = qqv;
  __syncthreads();
  if (tid < 256) {
    float st = 0.f, qt = 0.f;
#pragma unroll
    for (int r = 0; r < 8; ++r) {
      st += sS[r][tid];
      qt += sQ[r][tid];
    }
    const float m = st * (1.0f / C_IN);
    mu[p0 + tid] = m;
    rs[p0 + tid] = rsqrtf(qt * (1.0f / C_IN) - m * m + 1e-5f);
  }
}

// ---------------------------------------------------------------------------
// Pass 2 (new, R0-shaped): GEMM + LN epilogue + GELU.
//   Block = 64 px x 192 outs; grid 4096 (2 o-groups per px-tile; xb re-read
//   is L3-served).  4 waves: (wm = px half) x (wn = 96-out half).
//   k-loop: 12 steps of BK=32 with double-buffered LDS transpose staging
//   (load bf16x4 pairs from xb[c][s], write bf16x2 -> Xs[px][c], 2-way=free;
//   a-frag ds_read conflict-free via 17-word row stride).  B-frags from
//   L2-resident tiled Wt: one fully-coalesced 16B/lane load per (half,otile).
//   One barrier per k-step; stage loads issued before compute (T14).
// ---------------------------------------------------------------------------
__global__ __launch_bounds__(256, 4) void ppl_gemm3_kernel(const __bf16* __restrict__ xb,
                                                           const __bf16* __restrict__ Wt,
                                                           const float* __restrict__ mug,
                                                           const float* __restrict__ rsg,
                                                           const float* __restrict__ t1g,
                                                           const float* __restrict__ t2g,
                                                           float* __restrict__ out) {
  __shared__ __bf16 Xs[2][BP * ROW2];   // 2 x 4352 B
  __shared__ float mu_s[BP];
  __shared__ float rs_s[BP];

  const int tid = threadIdx.x;
  const int w = tid >> 6;
  const int lane = tid & 63;
  const int col = lane & 31;
  const int hi = lane >> 5;
  const int wm = w >> 1;          // px half (32 px)
  const int wn = w & 1;           // out half (96 outs)
  const int bid = blockIdx.x;
  const int og = bid & 1;         // out group (192 outs)
  const int pt = bid >> 1;
  const int p0 = pt * BP;
  const int b = p0 >> 12;
  const int s0 = p0 & 4095;

  if (tid < BP) {
    mu_s[tid] = mug[p0 + tid];
    rs_s[tid] = rsg[p0 + tid];
  }

  // staging map: v = px quad (4v..4v+3), c2 = channel pair (2c2, 2c2+1)
  const int v = tid & 15;
  const int c2 = tid >> 4;
  const __bf16* xsrc = xb + (((size_t)(b * C_IN) + 2 * c2) << 12) + s0 + 4 * v;
  __bf16* xdst = &Xs[0][0] + (4 * v) * ROW2 + 2 * c2;

  // B pointers: wave's 3 otiles (each 32 outs), tiled Wt, lane-coalesced
  const int otb = og * 6 + wn * 3;
  const __bf16* wt0 = Wt + (((size_t)(otb + 0) * 48 + hi) << 8) + col * 8;
  const __bf16* wt1 = Wt + (((size_t)(otb + 1) * 48 + hi) << 8) + col * 8;
  const __bf16* wt2 = Wt + (((size_t)(otb + 2) * 48 + hi) << 8) + col * 8;

  // A read base (buffer 0); buffer toggles by += / -= BP*ROW2
  const __bf16* abase = &Xs[0][0] + (wm * 32 + col) * ROW2 + hi * 8;

  f32x16 acc[3];
#pragma unroll
  for (int n = 0; n < 3; ++n)
#pragma unroll
    for (int r = 0; r < 16; ++r) acc[n][r] = 0.f;

  bf16x4 sA, sB;
#define SLOAD(K)                                                    \
  {                                                                 \
    const __bf16* sp_ = xsrc + ((size_t)(K) << 12);                 \
    sA = *reinterpret_cast<const bf16x4*>(sp_);                     \
    sB = *reinterpret_cast<const bf16x4*>(sp_ + SPB);               \
  }
#define SWRITE(bi)                                                  \
  {                                                                 \
    __bf16* d_ = xdst + (bi) * (BP * ROW2);                         \
    _Pragma("unroll") for (int r_ = 0; r_ < 4; ++r_) {              \
      bf16x2 pr_;                                                   \
      pr_[0] = sA[r_];                                              \
      pr_[1] = sB[r_];                                              \
      *reinterpret_cast<bf16x2*>(d_ + r_ * ROW2) = pr_;             \
    }                                                               \
  }

  // prologue: stage step 0 into buffer 0
  SLOAD(0);
  SWRITE(0);
  __syncthreads();

#pragma unroll 2
  for (int it = 0; it < 12; ++it) {
    if (it < 11) SLOAD(32 * (it + 1));  // issue early (T14)

    const __bf16* ap = abase + (it & 1) * (BP * ROW2);
    const bf16x8 a0 = *reinterpret_cast<const bf16x8*>(ap);
    const bf16x8 a1 = *reinterpret_cast<const bf16x8*>(ap + 16);

    const int kofs = it * 1024;  // (4*it)*256 elements
    const bf16x8 b00 = *reinterpret_cast<const bf16x8*>(wt0 + kofs);
    const bf16x8 b01 = *reinterpret_cast<const bf16x8*>(wt1 + kofs);
    const bf16x8 b02 = *reinterpret_cast<const bf16x8*>(wt2 + kofs);
    const bf16x8 b10 = *reinterpret_cast<const bf16x8*>(wt0 + kofs + 512);
    const bf16x8 b11 = *reinterpret_cast<const bf16x8*>(wt1 + kofs + 512);
    const bf16x8 b12 = *reinterpret_cast<const bf16x8*>(wt2 + kofs + 512);

    acc[0] = __builtin_amdgcn_mfma_f32_32x32x16_bf16(a0, b00, acc[0], 0, 0, 0);
    acc[1] = __builtin_amdgcn_mfma_f32_32x32x16_bf16(a0, b01, acc[1], 0, 0, 0);
    acc[2] = __builtin_amdgcn_mfma_f32_32x32x16_bf16(a0, b02, acc[2], 0, 0, 0);
    acc[0] = __builtin_amdgcn_mfma_f32_32x32x16_bf16(a1, b10, acc[0], 0, 0, 0);
    acc[1] = __builtin_amdgcn_mfma_f32_32x32x16_bf16(a1, b11, acc[1], 0, 0, 0);
    acc[2] = __builtin_amdgcn_mfma_f32_32x32x16_bf16(a1, b12, acc[2], 0, 0, 0);

    if (it < 11) SWRITE((it + 1) & 1);  // write late
    __syncthreads();
  }
#undef SLOAD
#undef SWRITE

  // ---- epilogue: LN correction + GELU + f32x4 NCHW stores ----
#pragma unroll
  for (int n = 0; n < 3; ++n) {
    const int o = og * 192 + wn * 96 + n * 32 + col;
    const float t1v = t1g[o];
    const float t2v = t2g[o];
    float* op = out + (((size_t)(b * C_OUT + o)) << 12) + s0 + wm * 32;
#pragma unroll
    for (int qd = 0; qd < 4; ++qd) {
      const int pr = qd * 8 + hi * 4;  // px within wave's 32-block
      const f32x4 mu4 = *reinterpret_cast<const f32x4*>(&mu_s[wm * 32 + pr]);
      const f32x4 rs4 = *reinterpret_cast<const f32x4*>(&rs_s[wm * 32 + pr]);
      f32x4 y;
#pragma unroll
      for (int r = 0; r < 4; ++r) {
        const float val = rs4[r] * (acc[n][qd * 4 + r] - mu4[r] * t1v) + t2v;
        y[r] = gelu_fast(val);
      }
      *reinterpret_cast<f32x4*>(op + pr) = y;
    }
  }
}

// ---------------------------------------------------------------------------
// Fallback (R4/R5): fully fused single-pass kernel (measured 193 us), used
// only if ws_size can't hold the bf16 x copy.
// ---------------------------------------------------------------------------
__global__ __launch_bounds__(256, 3) void ppl_fused_kernel(const float* __restrict__ x,
                                                           const __bf16* __restrict__ Wp,
                                                           const float* __restrict__ t1g,
                                                           const float* __restrict__ t2g,
                                                           float* __restrict__ out) {
  __shared__ __bf16 Xs[BP][LDK];
  __shared__ float sS[4][BP];
  __shared__ float sQ[4][BP];
  __shared__ float mu_s[BP];
  __shared__ float rs_s[BP];

  const int tid = threadIdx.x;
  const int w = tid >> 6;
  const int lane = tid & 63;
  const int q = tid & 15;
  const int j = tid >> 4;
  const int col = lane & 31;
  const int hi = lane >> 5;
  const int p0 = blockIdx.x * BP;
  const int b = p0 >> 12;
  const int s0 = p0 & 4095;
  const int ob = w * 96;

  const float* xq = x + (size_t)b * (C_IN * SPB) + s0 + 4 * q;

  f32x4 LA[12], LB[12];
#pragma unroll
  for (int i = 0; i < 3; ++i)
#pragma unroll
    for (int m = 0; m < 4; ++m)
      LA[i * 4 + m] = *reinterpret_cast<const f32x4*>(xq + (size_t)(64 * i + 4 * j + m) * SPB);
#pragma unroll
  for (int i = 0; i < 3; ++i)
#pragma unroll
    for (int m = 0; m < 4; ++m)
      LB[i * 4 + m] = *reinterpret_cast<const f32x4*>(xq + (size_t)(64 * (i + 3) + 4 * j + m) * SPB);

  float ss[4] = {0.f, 0.f, 0.f, 0.f};
  float qq[4] = {0.f, 0.f, 0.f, 0.f};

#define PROCESS(L, ibase)                                                   \
  {                                                                         \
    _Pragma("unroll") for (int i = 0; i < 3; ++i) {                         \
      _Pragma("unroll") for (int r = 0; r < 4; ++r) {                       \
        const float f0 = L[i * 4 + 0][r];                                   \
        const float f1 = L[i * 4 + 1][r];                                   \
        const float f2 = L[i * 4 + 2][r];                                   \
        const float f3 = L[i * 4 + 3][r];                                   \
        ss[r] += (f0 + f1) + (f2 + f3);                                     \
        qq[r] += (f0 * f0 + f1 * f1) + (f2 * f2 + f3 * f3);                 \
        bf16x4 pk;                                                          \
        pk[0] = (__bf16)f0; pk[1] = (__bf16)f1;                             \
        pk[2] = (__bf16)f2; pk[3] = (__bf16)f3;                             \
        *reinterpret_cast<bf16x4*>(&Xs[4 * q + r][64 * ((ibase) + i) + 4 * j]) = pk; \
      }                                                                     \
    }                                                                       \
  }
  PROCESS(LA, 0)
  PROCESS(LB, 3)
#undef PROCESS

#pragma unroll
  for (int r = 0; r < 4; ++r) {
    ss[r] += __shfl_xor(ss[r], 16);
    ss[r] += __shfl_xor(ss[r], 32);
    qq[r] += __shfl_xor(qq[r], 16);
    qq[r] += __shfl_xor(qq[r], 32);
  }
  if (lane < 16) {
#pragma unroll
    for (int r = 0; r < 4; ++r) {
      sS[w][4 * lane + r] = ss[r];
      sQ[w][4 * lane + r] = qq[r];
    }
  }
  __syncthreads();
  if (tid < BP) {
    const float st = sS[0][tid] + sS[1][tid] + sS[2][tid] + sS[3][tid];
    const float qt = sQ[0][tid] + sQ[1][tid] + sQ[2][tid] + sQ[3][tid];
    const float m = st * (1.0f / C_IN);
    mu_s[tid] = m;
    rs_s[tid] = rsqrtf(qt * (1.0f / C_IN) - m * m + 1e-5f);
  }
  __syncthreads();

  const __bf16* wp0 = Wp + (size_t)(ob + col) * C_IN + hi * 8;
  const __bf16* wp1 = wp0 + 32 * C_IN;
  const __bf16* wp2 = wp0 + 64 * C_IN;
  const __bf16* xs0 = &Xs[col][hi * 8];
  const __bf16* xs1 = &Xs[32 + col][hi * 8];

  f32x16 acc[2][3];
#pragma unroll
  for (int m = 0; m < 2; ++m)
#pragma unroll
    for (int n = 0; n < 3; ++n)
#pragma unroll
      for (int r = 0; r < 16; ++r) acc[m][n][r] = 0.f;

#define LOADB(dst, kk)                                     \
  {                                                        \
    dst[0] = *reinterpret_cast<const bf16x8*>(wp0 + (kk)); \
    dst[1] = *reinterpret_cast<const bf16x8*>(wp1 + (kk)); \
    dst[2] = *reinterpret_cast<const bf16x8*>(wp2 + (kk)); \
  }
#define STEP(bb, kk)                                                                    \
  {                                                                                     \
    const bf16x8 a0 = *reinterpret_cast<const bf16x8*>(xs0 + (kk));                     \
    const bf16x8 a1 = *reinterpret_cast<const bf16x8*>(xs1 + (kk));                     \
    acc[0][0] = __builtin_amdgcn_mfma_f32_32x32x16_bf16(a0, bb[0], acc[0][0], 0, 0, 0); \
    acc[0][1] = __builtin_amdgcn_mfma_f32_32x32x16_bf16(a0, bb[1], acc[0][1], 0, 0, 0); \
    acc[0][2] = __builtin_amdgcn_mfma_f32_32x32x16_bf16(a0, bb[2], acc[0][2], 0, 0, 0); \
    acc[1][0] = __builtin_amdgcn_mfma_f32_32x32x16_bf16(a1, bb[0], acc[1][0], 0, 0, 0); \
    acc[1][1] = __builtin_amdgcn_mfma_f32_32x32x16_bf16(a1, bb[1], acc[1][1], 0, 0, 0); \
    acc[1][2] = __builtin_amdgcn_mfma_f32_32x32x16_bf16(a1, bb[2], acc[1][2], 0, 0, 0); \
  }
  {
    bf16x8 bA[3], bB[3];
    LOADB(bA, 0);
#pragma unroll
    for (int it = 0; it < 12; ++it) {
      const int k = it * 32;
      LOADB(bB, k + 16);
      STEP(bA, k);
      if (it < 11) LOADB(bA, k + 32);
      STEP(bB, k + 16);
    }
  }
#undef LOADB
#undef STEP

  const float t1v[3] = {t1g[ob + col], t1g[ob + 32 + col], t1g[ob + 64 + col]};
  const float t2v[3] = {t2g[ob + col], t2g[ob + 32 + col], t2g[ob + 64 + col]};
  float* outp = out + (((size_t)(b * C_OUT + ob + col)) << 12) + s0;
#pragma unroll
  for (int nf = 0; nf < 3; ++nf) {
    float* op = outp + ((size_t)nf << 17);
#pragma unroll
    for (int m = 0; m < 2; ++m) {
#pragma unroll
      for (int qd = 0; qd < 4; ++qd) {
        const int pr = m * 32 + qd * 8 + hi * 4;
        const f32x4 mu4 = *reinterpret_cast<const f32x4*>(&mu_s[pr]);
        const f32x4 rs4 = *reinterpret_cast<const f32x4*>(&rs_s[pr]);
        f32x4 y;
#pragma unroll
        for (int r = 0; r < 4; ++r) {
          const float val = rs4[r] * (acc[m][nf][qd * 4 + r] - mu4[r] * t1v[nf]) + t2v[nf];
          y[r] = gelu_fast(val);
        }
        *reinterpret_cast<f32x4*>(op + pr) = y;
      }
    }
  }
}

// ---------------------------------------------------------------------------
extern "C" void kernel_launch(void* const* d_in, const int* in_sizes, int n_in,
                              void* d_out, int out_size, void* d_ws, size_t ws_size,
                              hipStream_t stream) {
  const float* x = (const float*)d_in[0];
  const float* gamma = (const float*)d_in[1];
  const float* beta = (const float*)d_in[2];
  const float* W = (const float*)d_in[3];
  const float* bias = (const float*)d_in[4];
  float* out = (float*)d_out;

  // workspace layout
  __bf16* Wp = (__bf16*)d_ws;                   // 294912 B (row-major, fallback)
  __bf16* Wt = Wp + C_OUT * C_IN;               // 294912 B (tiled, gemm3)
  float* t1 = (float*)(Wt + C_OUT * C_IN);      // 1536 B
  float* t2 = t1 + C_OUT;                       // 1536 B
  float* mu = t2 + C_OUT;                       // NPIX floats
  float* rs = mu + NPIX;                        // NPIX floats
  __bf16* xb = (__bf16*)(rs + NPIX);            // NPIX * C_IN bf16 = 100.7 MB

  const size_t need = 2 * (size_t)C_OUT * C_IN * 2 + 2 * C_OUT * 4 +
                      2 * (size_t)NPIX * 4 + (size_t)NPIX * C_IN * 2;

  ppl_prep_kernel<<<C_OUT, 128, 0, stream>>>(W, gamma, beta, bias, Wp, Wt, t1, t2);

  if (ws_size >= need) {
    ppl_stats_cast_kernel<<<NPIX / 256, 512, 0, stream>>>(x, xb, mu, rs);
    ppl_gemm3_kernel<<<(NPIX / BP) * 2, 256, 0, stream>>>(xb, Wt, mu, rs, t1, t2, out);
  } else {
    ppl_fused_kernel<<<NPIX / BP, 256, 0, stream>>>(x, Wp, t1, t2, out);
  }
}